// Round 1
// baseline (3824.880 us; speedup 1.0000x reference)
//
#include <hip/hip_runtime.h>

// GGLR_52630529245706 — fp32 correctness-first baseline.
// Stages:
//   1. proj:    Wp[k] = p @ Ws[k]^T + bs[k]; Wq[k] = q @ Ws[k]^T + bs[k]   (ws)
//   2. pq_gemm: p_k[k] = leaky((A^T @ Wp[k]) / D_out),  q_k[k] = leaky((A @ Wq[k]) / D_in)
//               degrees computed in-pass (each j-tile block reads its full A stripe)
//   3. dec:     dec = p_k[2] @ Wd^T + bd                                   (ws)
//   4. eij:     e[i,j] = dot(dec[i], q_k[2][j]) * a * d^b * exp(c*d)

constexpr int N_ = 8192;
constexpr int D_ = 128;

// ---------------------------------------------------------------------------
// small GEMM tile: Out[n,e] = sum_d X[n,d] * W[e,d] + bias[e]
// X: [N_,128], W: [128,128] row-major [e][d]. Block: 256 thr, 128x128 tile.
// ---------------------------------------------------------------------------
__device__ __forceinline__ void small_gemm_tile(
    const float* __restrict__ X, const float* __restrict__ W,
    const float* __restrict__ bias, float* __restrict__ Out, int n0)
{
    __shared__ float XsT[16][132];  // [dd][n]
    __shared__ float WsT[16][132];  // [dd][e]
    const int t  = threadIdx.x;
    const int tx = t & 15;          // e-group: e = tx*8 + cc
    const int ty = t >> 4;          // n-group: n = n0 + ty*8 + rr
    float acc[8][8] = {};

    for (int d0 = 0; d0 < 128; d0 += 16) {
        __syncthreads();
        const int r = t >> 1, c = t & 1;
        const float* sx = X + (size_t)(n0 + r) * 128 + d0 + c * 8;
        float4 v0 = *(const float4*)sx;
        float4 v1 = *(const float4*)(sx + 4);
        XsT[c*8+0][r] = v0.x; XsT[c*8+1][r] = v0.y; XsT[c*8+2][r] = v0.z; XsT[c*8+3][r] = v0.w;
        XsT[c*8+4][r] = v1.x; XsT[c*8+5][r] = v1.y; XsT[c*8+6][r] = v1.z; XsT[c*8+7][r] = v1.w;
        const float* sw = W + (size_t)r * 128 + d0 + c * 8;
        float4 w0 = *(const float4*)sw;
        float4 w1 = *(const float4*)(sw + 4);
        WsT[c*8+0][r] = w0.x; WsT[c*8+1][r] = w0.y; WsT[c*8+2][r] = w0.z; WsT[c*8+3][r] = w0.w;
        WsT[c*8+4][r] = w1.x; WsT[c*8+5][r] = w1.y; WsT[c*8+6][r] = w1.z; WsT[c*8+7][r] = w1.w;
        __syncthreads();
#pragma unroll
        for (int dd = 0; dd < 16; ++dd) {
            float xa[8], wb[8];
            *(float4*)&xa[0] = *(const float4*)&XsT[dd][ty*8];
            *(float4*)&xa[4] = *(const float4*)&XsT[dd][ty*8+4];
            *(float4*)&wb[0] = *(const float4*)&WsT[dd][tx*8];
            *(float4*)&wb[4] = *(const float4*)&WsT[dd][tx*8+4];
#pragma unroll
            for (int rr = 0; rr < 8; ++rr)
#pragma unroll
                for (int cc = 0; cc < 8; ++cc)
                    acc[rr][cc] += xa[rr] * wb[cc];
        }
    }

    float bv[8];
    *(float4*)&bv[0] = *(const float4*)&bias[tx*8];
    *(float4*)&bv[4] = *(const float4*)&bias[tx*8+4];
#pragma unroll
    for (int rr = 0; rr < 8; ++rr) {
        const int n = n0 + ty*8 + rr;
        float o[8];
#pragma unroll
        for (int cc = 0; cc < 8; ++cc) o[cc] = acc[rr][cc] + bv[cc];
        *(float4*)&Out[(size_t)n*128 + tx*8]     = *(float4*)&o[0];
        *(float4*)&Out[(size_t)n*128 + tx*8 + 4] = *(float4*)&o[4];
    }
}

__global__ void proj_kernel(const float* __restrict__ p, const float* __restrict__ q,
                            const float* __restrict__ Ws, const float* __restrict__ bs,
                            float* __restrict__ Wp, float* __restrict__ Wq)
{
    const int m = blockIdx.y;            // 0..5
    const int side = m / 3, k = m % 3;
    const float* X = side ? q : p;
    float* Out = (side ? Wq : Wp) + (size_t)k * N_ * D_;
    small_gemm_tile(X, Ws + (size_t)k * D_ * D_, bs + (size_t)k * D_, Out,
                    blockIdx.x * 128);
}

__global__ void dec_kernel(const float* __restrict__ pk2, const float* __restrict__ Wd,
                           const float* __restrict__ bd, float* __restrict__ dec)
{
    small_gemm_tile(pk2, Wd, bd, dec, blockIdx.x * 128);
}

// ---------------------------------------------------------------------------
// pq_gemm: side 0: C[j,d] = leaky((sum_i A[i,j]*W[i,d]) / sum_i A[i,j])
//          side 1: C[j,d] = leaky((sum_i A[j,i]*W[i,d]) / sum_i A[j,i])
// Block: 256 thr, output tile 128 j x 128 d, micro 8x8, BI=16.
// ---------------------------------------------------------------------------
__global__ void pq_gemm(const float* __restrict__ A,
                        const float* __restrict__ Wp, const float* __restrict__ Wq,
                        float* __restrict__ out_pk, float* __restrict__ out_qk)
{
    const int j0   = blockIdx.x * 128;
    const int k    = blockIdx.y;
    const int side = blockIdx.z;
    const float* Wsrc = (side ? Wq : Wp) + (size_t)k * N_ * D_;
    float* outp       = (side ? out_qk : out_pk) + (size_t)k * N_ * D_;

    __shared__ float As[16][132];       // [ii][jj]
    __shared__ float Wls[16][132];      // [ii][dd]
    __shared__ float degtmp[16][128];
    __shared__ float deg[128];

    const int t  = threadIdx.x;
    const int tx = t & 15;              // d-group
    const int ty = t >> 4;              // j-group
    float acc[8][8] = {};
    float dsum[8] = {0.f,0.f,0.f,0.f,0.f,0.f,0.f,0.f};

    for (int i0 = 0; i0 < N_; i0 += 16) {
        __syncthreads();
        if (side == 0) {
            const int ii = t >> 4;
            const int jj = (t & 15) * 8;
            const float* src = A + (size_t)(i0 + ii) * N_ + j0 + jj;
            float4 v0 = *(const float4*)src;
            float4 v1 = *(const float4*)(src + 4);
            *(float4*)&As[ii][jj]     = v0;
            *(float4*)&As[ii][jj + 4] = v1;
            dsum[0] += v0.x; dsum[1] += v0.y; dsum[2] += v0.z; dsum[3] += v0.w;
            dsum[4] += v1.x; dsum[5] += v1.y; dsum[6] += v1.z; dsum[7] += v1.w;
        } else {
            const int jj = t >> 1, c = t & 1;
            const float* src = A + (size_t)(j0 + jj) * N_ + i0 + c * 8;
            float4 v0 = *(const float4*)src;
            float4 v1 = *(const float4*)(src + 4);
            As[c*8+0][jj] = v0.x; As[c*8+1][jj] = v0.y; As[c*8+2][jj] = v0.z; As[c*8+3][jj] = v0.w;
            As[c*8+4][jj] = v1.x; As[c*8+5][jj] = v1.y; As[c*8+6][jj] = v1.z; As[c*8+7][jj] = v1.w;
            dsum[0] += v0.x + v0.y + v0.z + v0.w + v1.x + v1.y + v1.z + v1.w;
        }
        {
            const int ii = t >> 4;
            const int dd = (t & 15) * 8;
            const float* srcw = Wsrc + (size_t)(i0 + ii) * D_ + dd;
            *(float4*)&Wls[ii][dd]     = *(const float4*)srcw;
            *(float4*)&Wls[ii][dd + 4] = *(const float4*)(srcw + 4);
        }
        __syncthreads();
#pragma unroll
        for (int ii = 0; ii < 16; ++ii) {
            float aj[8], wd[8];
            *(float4*)&aj[0] = *(const float4*)&As[ii][ty*8];
            *(float4*)&aj[4] = *(const float4*)&As[ii][ty*8+4];
            *(float4*)&wd[0] = *(const float4*)&Wls[ii][tx*8];
            *(float4*)&wd[4] = *(const float4*)&Wls[ii][tx*8+4];
#pragma unroll
            for (int rr = 0; rr < 8; ++rr)
#pragma unroll
                for (int cc = 0; cc < 8; ++cc)
                    acc[rr][cc] += aj[rr] * wd[cc];
        }
    }

    // degree reduction
    __syncthreads();
    if (side == 0) {
        const int ii = t >> 4, jj = (t & 15) * 8;
#pragma unroll
        for (int r = 0; r < 8; ++r) degtmp[ii][jj + r] = dsum[r];
    } else {
        const int jj = t >> 1, c = t & 1;
        degtmp[c][jj] = dsum[0];
    }
    __syncthreads();
    if (t < 128) {
        float s = 0.f;
        if (side == 0) {
#pragma unroll
            for (int ii = 0; ii < 16; ++ii) s += degtmp[ii][t];
        } else {
            s = degtmp[0][t] + degtmp[1][t];
        }
        deg[t] = s;
    }
    __syncthreads();

#pragma unroll
    for (int rr = 0; rr < 8; ++rr) {
        const int j = j0 + ty*8 + rr;
        const float degv = deg[ty*8 + rr];
        float o[8];
#pragma unroll
        for (int cc = 0; cc < 8; ++cc) {
            float v = acc[rr][cc] / degv;
            o[cc] = (v >= 0.f) ? v : 0.01f * v;
        }
        *(float4*)&outp[(size_t)j * D_ + tx*8]     = *(float4*)&o[0];
        *(float4*)&outp[(size_t)j * D_ + tx*8 + 4] = *(float4*)&o[4];
    }
}

// ---------------------------------------------------------------------------
// eij: e[i,j] = (sum_d dec[i,d]*q2[j,d]) * a * dist^b * exp(c*dist)
// Block: 256 thr, 128x128 tile, K=128 in 4 chunks of 32.
// ---------------------------------------------------------------------------
__global__ void eij_kernel(const float* __restrict__ dec, const float* __restrict__ q2,
                           const float* __restrict__ dist,
                           const float* __restrict__ pa, const float* __restrict__ pb,
                           const float* __restrict__ pc, float* __restrict__ eout)
{
    const int i0 = blockIdx.y * 128;
    const int j0 = blockIdx.x * 128;
    __shared__ float DsT[32][132];  // [dd][i]
    __shared__ float QsT[32][132];  // [dd][j]
    const int t  = threadIdx.x;
    const int tx = t & 15;          // j-group
    const int ty = t >> 4;          // i-group
    float acc[8][8] = {};

    for (int d0 = 0; d0 < D_; d0 += 32) {
        __syncthreads();
        const int r = t >> 1, c = t & 1;
        {
            const float* s1 = dec + (size_t)(i0 + r) * D_ + d0 + c * 16;
            float4 a0 = *(const float4*)s1;
            float4 a1 = *(const float4*)(s1 + 4);
            float4 a2 = *(const float4*)(s1 + 8);
            float4 a3 = *(const float4*)(s1 + 12);
            DsT[c*16+ 0][r] = a0.x; DsT[c*16+ 1][r] = a0.y; DsT[c*16+ 2][r] = a0.z; DsT[c*16+ 3][r] = a0.w;
            DsT[c*16+ 4][r] = a1.x; DsT[c*16+ 5][r] = a1.y; DsT[c*16+ 6][r] = a1.z; DsT[c*16+ 7][r] = a1.w;
            DsT[c*16+ 8][r] = a2.x; DsT[c*16+ 9][r] = a2.y; DsT[c*16+10][r] = a2.z; DsT[c*16+11][r] = a2.w;
            DsT[c*16+12][r] = a3.x; DsT[c*16+13][r] = a3.y; DsT[c*16+14][r] = a3.z; DsT[c*16+15][r] = a3.w;
        }
        {
            const float* s2 = q2 + (size_t)(j0 + r) * D_ + d0 + c * 16;
            float4 a0 = *(const float4*)s2;
            float4 a1 = *(const float4*)(s2 + 4);
            float4 a2 = *(const float4*)(s2 + 8);
            float4 a3 = *(const float4*)(s2 + 12);
            QsT[c*16+ 0][r] = a0.x; QsT[c*16+ 1][r] = a0.y; QsT[c*16+ 2][r] = a0.z; QsT[c*16+ 3][r] = a0.w;
            QsT[c*16+ 4][r] = a1.x; QsT[c*16+ 5][r] = a1.y; QsT[c*16+ 6][r] = a1.z; QsT[c*16+ 7][r] = a1.w;
            QsT[c*16+ 8][r] = a2.x; QsT[c*16+ 9][r] = a2.y; QsT[c*16+10][r] = a2.z; QsT[c*16+11][r] = a2.w;
            QsT[c*16+12][r] = a3.x; QsT[c*16+13][r] = a3.y; QsT[c*16+14][r] = a3.z; QsT[c*16+15][r] = a3.w;
        }
        __syncthreads();
#pragma unroll
        for (int dd = 0; dd < 32; ++dd) {
            float av[8], bv[8];
            *(float4*)&av[0] = *(const float4*)&DsT[dd][ty*8];
            *(float4*)&av[4] = *(const float4*)&DsT[dd][ty*8+4];
            *(float4*)&bv[0] = *(const float4*)&QsT[dd][tx*8];
            *(float4*)&bv[4] = *(const float4*)&QsT[dd][tx*8+4];
#pragma unroll
            for (int rr = 0; rr < 8; ++rr)
#pragma unroll
                for (int cc = 0; cc < 8; ++cc)
                    acc[rr][cc] += av[rr] * bv[cc];
        }
    }

    const float a_ = pa[0], b_ = pb[0], c_ = pc[0];
#pragma unroll
    for (int rr = 0; rr < 8; ++rr) {
        const int i = i0 + ty*8 + rr;
        const float* dr = dist + (size_t)i * N_ + j0 + tx*8;
        float4 d0v = *(const float4*)dr;
        float4 d1v = *(const float4*)(dr + 4);
        float dv[8] = {d0v.x, d0v.y, d0v.z, d0v.w, d1v.x, d1v.y, d1v.z, d1v.w};
        float o[8];
#pragma unroll
        for (int cc = 0; cc < 8; ++cc) {
            const float d = dv[cc];
            const float fx = a_ * __expf(b_ * __logf(d) + c_ * d);
            o[cc] = acc[rr][cc] * fx;
        }
        *(float4*)&eout[(size_t)i * N_ + j0 + tx*8]     = *(float4*)&o[0];
        *(float4*)&eout[(size_t)i * N_ + j0 + tx*8 + 4] = *(float4*)&o[4];
    }
}

extern "C" void kernel_launch(void* const* d_in, const int* in_sizes, int n_in,
                              void* d_out, int out_size, void* d_ws, size_t ws_size,
                              hipStream_t stream)
{
    (void)in_sizes; (void)n_in; (void)out_size; (void)ws_size;
    const float* p    = (const float*)d_in[0];
    const float* q    = (const float*)d_in[1];
    const float* A    = (const float*)d_in[2];
    const float* dist = (const float*)d_in[3];
    const float* Ws   = (const float*)d_in[4];
    const float* bs   = (const float*)d_in[5];
    const float* Wd   = (const float*)d_in[6];
    const float* bd   = (const float*)d_in[7];
    const float* pa   = (const float*)d_in[8];
    const float* pb   = (const float*)d_in[9];
    const float* pc   = (const float*)d_in[10];

    float* out    = (float*)d_out;
    float* out_pk = out;                              // [3,N,D]
    float* out_qk = out + (size_t)3 * N_ * D_;        // [3,N,D]
    float* out_e  = out + (size_t)6 * N_ * D_;        // [N,N]

    float* Wp  = (float*)d_ws;                        // [3,N,D]
    float* Wq  = Wp + (size_t)3 * N_ * D_;            // [3,N,D]
    float* dec = Wq + (size_t)3 * N_ * D_;            // [N,D]

    proj_kernel<<<dim3(64, 6), 256, 0, stream>>>(p, q, Ws, bs, Wp, Wq);
    pq_gemm<<<dim3(64, 3, 2), 256, 0, stream>>>(A, Wp, Wq, out_pk, out_qk);
    dec_kernel<<<dim3(64), 256, 0, stream>>>(out_pk + (size_t)2 * N_ * D_, Wd, bd, dec);
    eij_kernel<<<dim3(64, 64), 256, 0, stream>>>(dec, out_qk + (size_t)2 * N_ * D_,
                                                 dist, pa, pb, pc, out_e);
}